// Round 2
// baseline (223.758 us; speedup 1.0000x reference)
//
#include <hip/hip_runtime.h>
#include <cstdint>
#include <cstddef>

#define TT 512
#define BB 128
#define EE 128
#define SS 1024
#define NEG_INF (-1e30f)

typedef _Float16 half8 __attribute__((ext_vector_type(8)));
typedef float floatx4 __attribute__((ext_vector_type(4)));

// ---------- fp16 helpers ----------
__device__ __forceinline__ unsigned int pkh(float x, float y) {
    _Float16 hx = (_Float16)x, hy = (_Float16)y;
    unsigned short bx, by;
    __builtin_memcpy(&bx, &hx, 2); __builtin_memcpy(&by, &hy, 2);
    return (unsigned int)bx | ((unsigned int)by << 16);
}

// ============================================================
// prefixF: per-b prefix sums + range-max precompute.  (unchanged)
// ============================================================
__global__ __launch_bounds__(64) void prefixF(
    const float* __restrict__ d1, const float* __restrict__ d2,
    const float* __restrict__ u,
    float* __restrict__ F, float* __restrict__ Bv,
    float* __restrict__ d2T, float* __restrict__ FT,
    float* __restrict__ BvT, float* __restrict__ CST,
    float* __restrict__ CMT, float* __restrict__ HT)
{
    const int b = blockIdx.x;
    const int lane = threadIdx.x;
    const int t0 = lane * 8;

    float l1[8], l2[8], g[8];
#pragma unroll
    for (int j = 0; j < 8; ++j) {
        const int t = t0 + j;
        l1[j] = d1[t * BB + b];
        l2[j] = d2[t * BB + b];
        g[j] = u[t * BB + b] - l1[j] - l2[j];
    }
    float p[8], s = 0.f;
#pragma unroll
    for (int j = 0; j < 8; ++j) { s += g[j]; p[j] = s; }

    float v = s;
#pragma unroll
    for (int off = 1; off < 64; off <<= 1) {
        float o = __shfl_up(v, off);
        if (lane >= off) v += o;
    }
    const float excl = v - s;

    float Fv[8];
#pragma unroll
    for (int j = 0; j < 8; ++j) Fv[j] = excl + p[j];

#pragma unroll
    for (int j = 0; j < 8; ++j) {
        const int t = t0 + j;
        const float Fm1 = (j > 0) ? Fv[j - 1] : excl;
        const float Bvv = Fm1 - l1[j];
        F  [b * TT + t] = Fv[j];
        Bv [b * TT + t] = Bvv;
        d2T[b * TT + t] = l2[j];
        FT [t * BB + b] = Fv[j];
        BvT[t * BB + b] = Bvv;
    }

    // ---- range-max structures (chunk = 32 t = 4 lanes) ----
    float pm[8], sm[8];
    pm[0] = Fv[0];
#pragma unroll
    for (int j = 1; j < 8; ++j) pm[j] = fmaxf(pm[j - 1], Fv[j]);
    sm[7] = Fv[7];
#pragma unroll
    for (int j = 6; j >= 0; --j) sm[j] = fmaxf(sm[j + 1], Fv[j]);

    float pcar = NEG_INF, scar = NEG_INF;
#pragma unroll
    for (int off = 1; off <= 3; ++off) {
        float xu = __shfl_up(pm[7], off);
        if ((lane & 3) >= off) pcar = fmaxf(pcar, xu);
        float xd = __shfl_down(sm[0], off);
        if ((lane & 3) + off <= 3) scar = fmaxf(scar, xd);
    }

#pragma unroll
    for (int j = 0; j < 8; ++j) {
        const int t = t0 + j;
        const float Hv  = fmaxf(pcar, (j > 0) ? pm[j - 1] : NEG_INF);
        const float CSv = fmaxf(sm[j], scar);
        HT [t * BB + b] = Hv;
        CST[t * BB + b] = CSv;
    }
    if ((lane & 3) == 0)
        CMT[(lane >> 2) * BB + b] = fmaxf(sm[0], scar);
}

// ============================================================
// calcM3: one block per t (big-t first), 4 waves, NO LDS, NO
// barriers.  Each lane folds b and b+64 in-register; one wave
// owns each i and reduces over batch via 6-level shfl_xor
// butterfly (max is exactly associative/commutative -> exact).
// Wave w owns chunk c iff (c&3)==w; diag chunk = statically
// unrolled register suffix scan (no dependent-load chain).
// K (suffix chunk max) maintained as running register.
// ============================================================
__global__ __launch_bounds__(256) void calcM3(
    const float* __restrict__ FT, const float* __restrict__ BvT,
    const float* __restrict__ CST, const float* __restrict__ CMT,
    const float* __restrict__ HT, const float* __restrict__ u,
    float* __restrict__ m)
{
    const int t = (TT - 1) - (int)blockIdx.x;   // descending t: balance
    const int ct = t >> 5;
    const int ilo = ct << 5;
    const int tid = threadIdx.x;
    const int w = tid >> 6, lane = tid & 63;
    const int b0 = lane, b1 = lane + 64;

    const float Ft0 = FT[t * BB + b0], Ft1 = FT[t * BB + b1];
    float* mrow = m + (size_t)t * SS;

    // ---------- diag chunk (owned by wave ct&3) ----------
    if (w == (ct & 3)) {
        float Fb0[32], Fb1[32];
#pragma unroll
        for (int j = 0; j < 32; ++j) {
            Fb0[j] = FT[(ilo + j) * BB + b0];
            Fb1[j] = FT[(ilo + j) * BB + b1];
        }
        float R0 = NEG_INF, R1 = NEG_INF;
#pragma unroll
        for (int j = 31; j >= 0; --j) {
            const int i = ilo + j;
            if (i <= t) {
                if (i < t) { R0 = fmaxf(R0, Fb0[j]); R1 = fmaxf(R1, Fb1[j]); }
                const float Bv0 = BvT[i * BB + b0], Bv1 = BvT[i * BB + b1];
                float c0 = fmaxf(Ft0 - fmaxf(Bv0, R0), Ft1 - fmaxf(Bv1, R1));
                float c1;
                if (i == t) c1 = fmaxf(u[t * BB + b0], u[t * BB + b1]);
                else        c1 = fmaxf(Ft0 - R0, Ft1 - R1);
#pragma unroll
                for (int off = 32; off >= 1; off >>= 1) {
                    c0 = fmaxf(c0, __shfl_xor(c0, off));
                    c1 = fmaxf(c1, __shfl_xor(c1, off));
                }
                if (lane == 0) *(float2*)&mrow[2 * i] = make_float2(c0, c1);
            }
        }
    }

    // ---------- off-diag chunks ----------
    float K0 = HT[t * BB + b0], K1 = HT[t * BB + b1];
    for (int c = ct - 1; c >= 0; --c) {
        if ((c & 3) == w) {
            const int i0 = c << 5;
#pragma unroll 4
            for (int j = 0; j < 32; ++j) {
                const int i = i0 + j;
                const float R0 = fmaxf(CST[i * BB + b0], K0);
                const float R1 = fmaxf(CST[i * BB + b1], K1);
                const float Bv0 = BvT[i * BB + b0], Bv1 = BvT[i * BB + b1];
                float c0 = fmaxf(Ft0 - fmaxf(Bv0, R0), Ft1 - fmaxf(Bv1, R1));
                float c1 = fmaxf(Ft0 - R0, Ft1 - R1);
#pragma unroll
                for (int off = 32; off >= 1; off >>= 1) {
                    c0 = fmaxf(c0, __shfl_xor(c0, off));
                    c1 = fmaxf(c1, __shfl_xor(c1, off));
                }
                if (lane == 0) *(float2*)&mrow[2 * i] = make_float2(c0, c1);
            }
        }
        K0 = fmaxf(K0, CMT[c * BB + b0]);
        K1 = fmaxf(K1, CMT[c * BB + b1]);
    }
}

// ============================================================
// phaseC_mfma: out[t,b,:] = sum_s min(a(i,t), m[t,s]) * V[b,s,:]
// 2-deep m prefetch (pmvA/pmvB ping-pong, loop unrolled x2,
// static register naming), 1-deep V prefetch, setprio on MFMA.
// ============================================================
#define WSO 0
#define VTO 2304
#define FRO 6912
#define S0O 7488
#define BVO 8064
#define LTO 8640
#define D2O 9088

__device__ __forceinline__ float tileQ(const float* Lt, int lo, int hi) {
    const int len = hi - lo + 1;                  // >= 1
    const int j = 31 - __builtin_clz(len);
    return fmaxf(Lt[j * 64 + lo], Lt[j * 64 + hi + 1 - (1 << j)]);
}

#define PREFETCH_M(CK, DST) do {                                          \
    const int i_ = 32 * (CK) + il;                                        \
    _Pragma("unroll")                                                     \
    for (int r8_ = 0; r8_ < 8; ++r8_) {                                   \
        DST[r8_] = *(const float2*)&m[(size_t)(t0 + 8 * g + r8_) * SS + 2 * i_]; \
    } } while (0)

#define PREFETCH_V(CK) do {                                               \
    const int i0_ = 32 * (CK) + 2 * vip, i1_ = i0_ + 1;                   \
    const float* p10_ = v1 + ((size_t)i0_ * BB + b) * EE;                 \
    const float* p11_ = v1 + ((size_t)i1_ * BB + b) * EE;                 \
    const float* p20_ = v2 + ((size_t)i0_ * BB + b) * EE;                 \
    const float* p21_ = v2 + ((size_t)i1_ * BB + b) * EE;                 \
    _Pragma("unroll")                                                     \
    for (int c_ = 0; c_ < 2; ++c_) {                                      \
        const int e0_ = 4 * veb + 32 * c_ + veh;                          \
        pv[4 * c_ + 0] = *(const float4*)&p10_[e0_];                      \
        pv[4 * c_ + 1] = *(const float4*)&p11_[e0_];                      \
        pv[4 * c_ + 2] = *(const float4*)&p20_[e0_];                      \
        pv[4 * c_ + 3] = *(const float4*)&p21_[e0_];                      \
    } } while (0)

#define CHUNK_BODY(CK, PMV, NXV, NXM) do {                                \
    const int ib = 32 * (CK);                                             \
    unsigned int wreg[8];                                                 \
    {                                                                     \
        const int i = ib + il;                                            \
        const float Ai = (i > 0) ? sh[FRO + i - 1] : 0.f;                 \
        const float Bi = sh[BVO + i];                                     \
        const bool below = (i < t0);                                      \
        const float S0i = below ? sh[S0O + i] : 0.f;                      \
        _Pragma("unroll")                                                 \
        for (int r8 = 0; r8 < 8; ++r8) {                                  \
            const int t_l = 8 * g + r8;                                   \
            const int t = t0 + t_l;                                       \
            float w0 = 0.f, w1 = 0.f;                                     \
            if (i <= t) {                                                 \
                float R;                                                  \
                if (below) {                                              \
                    const float qq = (t_l > 0) ? tileQ(Lt, 0, t_l - 1) : NEG_INF; \
                    R = fmaxf(S0i, qq);                                   \
                } else {                                                  \
                    const int li = i - t0;                                \
                    R = (t_l - 1 >= li) ? tileQ(Lt, li, t_l - 1) : NEG_INF; \
                }                                                         \
                const float2 mv = PMV[r8];                                \
                const float a0 = fmaxf(Ai, R) - fmaxf(Bi, R);             \
                const float a1 = (i == t) ? sh[D2O + t_l] : fmaxf(Bi - R, 0.f); \
                w0 = fminf(a0, mv.x);                                     \
                w1 = fminf(a1, mv.y);                                     \
            }                                                             \
            wreg[r8] = pkh(w0, w1);                                       \
        }                                                                 \
    }                                                                     \
    uint2 vreg[8];                                                        \
    _Pragma("unroll")                                                     \
    for (int c_ = 0; c_ < 2; ++c_) {                                      \
        const float4 xa = pv[4 * c_ + 0], xb = pv[4 * c_ + 1];            \
        const float4 ya = pv[4 * c_ + 2], yb = pv[4 * c_ + 3];            \
        vreg[4 * c_ + 0] = make_uint2(pkh(xa.x, ya.x), pkh(xb.x, yb.x));  \
        vreg[4 * c_ + 1] = make_uint2(pkh(xa.y, ya.y), pkh(xb.y, yb.y));  \
        vreg[4 * c_ + 2] = make_uint2(pkh(xa.z, ya.z), pkh(xb.z, yb.z));  \
        vreg[4 * c_ + 3] = make_uint2(pkh(xa.w, ya.w), pkh(xb.w, yb.w));  \
    }                                                                     \
    __syncthreads();                                                      \
    _Pragma("unroll")                                                     \
    for (int r8 = 0; r8 < 8; ++r8)                                        \
        ((unsigned int*)sh)[(8 * g + r8) * 36 + il] = wreg[r8];           \
    {                                                                     \
        unsigned int* vt = (unsigned int*)sh + VTO;                       \
        const int dw = 2 * vip;                                           \
        _Pragma("unroll")                                                 \
        for (int c_ = 0; c_ < 2; ++c_) {                                  \
            const int e0_ = 4 * veb + 32 * c_ + veh;                      \
            *(uint2*)&vt[(e0_ + 0) * 36 + dw] = vreg[4 * c_ + 0];         \
            *(uint2*)&vt[(e0_ + 1) * 36 + dw] = vreg[4 * c_ + 1];         \
            *(uint2*)&vt[(e0_ + 2) * 36 + dw] = vreg[4 * c_ + 2];         \
            *(uint2*)&vt[(e0_ + 3) * 36 + dw] = vreg[4 * c_ + 3];         \
        }                                                                 \
    }                                                                     \
    __syncthreads();                                                      \
    PREFETCH_V(NXV);                                                      \
    PREFETCH_M(NXM, PMV);                                                 \
    __builtin_amdgcn_s_setprio(1);                                        \
    {                                                                     \
        const _Float16* WsH = (const _Float16*)sh;                        \
        const _Float16* VtH = (const _Float16*)(sh + VTO);                \
        _Pragma("unroll")                                                 \
        for (int k2 = 0; k2 < 64; k2 += 32) {                             \
            const half8 av0 = *(const half8*)&WsH[(32 * wr + n) * 72 + kq + k2]; \
            const half8 av1 = *(const half8*)&WsH[(32 * wr + 16 + n) * 72 + kq + k2]; \
            _Pragma("unroll")                                             \
            for (int j = 0; j < 4; ++j) {                                 \
                const half8 bv = *(const half8*)&VtH[(64 * wc + 16 * j + n) * 72 + kq + k2]; \
                acc[0][j] = __builtin_amdgcn_mfma_f32_16x16x32_f16(av0, bv, acc[0][j], 0, 0, 0); \
                acc[1][j] = __builtin_amdgcn_mfma_f32_16x16x32_f16(av1, bv, acc[1][j], 0, 0, 0); \
            }                                                             \
        }                                                                 \
    }                                                                     \
    __builtin_amdgcn_s_setprio(0);                                        \
    } while (0)

__global__ __launch_bounds__(256) void phaseC_mfma(
    const float* __restrict__ F, const float* __restrict__ Bvg,
    const float* __restrict__ d2T, const float* __restrict__ m,
    const float* __restrict__ v1, const float* __restrict__ v2,
    float* __restrict__ out)
{
    const int b  = blockIdx.x & (BB - 1);
    const int k8 = blockIdx.x >> 7;
    // balanced remap: quartets {k8, k8+2, k8+4, k8+6} sum to 36 chunks.
    const int tt = 7 - (k8 ^ (((k8 + 2) >> 2) & 1));
    const int t0 = tt * 64;
    const int tid = threadIdx.x;

    __shared__ float sh[9152];

    // per-thread roles
    const int lane = tid & 63, w = tid >> 6;
    const int wr = w >> 1, wc = w & 1;            // 2x2 wave grid
    const int n = lane & 15;
    const int kq = (lane >> 4) * 8;
    const int il = tid & 31, g = tid >> 5;        // W staging
    const int veb = tid & 7;                      // V staging: e quad
    const int vip = ((tid >> 3) & 7) + 8 * wc;    // i-pair 0..15
    const int veh = wr * 64;                      // e half
    const float* Lt = &sh[LTO];
    const int nchunks = 2 * tt + 2;
    const int lastc = nchunks - 1;

    // ---------- pipeline registers ----------
    float4 pv[8];
    float2 pmvA[8], pmvB[8];

    const int nF = t0 + 64;
    for (int k = tid; k < nF; k += 256) {
        sh[FRO + k] = F[b * TT + k];
        sh[BVO + k] = Bvg[b * TT + k];
    }
    if (tid < 64) sh[D2O + tid] = d2T[b * TT + t0 + tid];

    // issue chunk-0/1 global loads early: latency hides under the
    // S0/Lt prologue scan below.
    PREFETCH_V(0);
    PREFETCH_M(0, pmvA);
    PREFETCH_M(min(1, lastc), pmvB);

    __syncthreads();

    // S0[k] = max F over [k, t0-1]   (NEG_INF for k >= t0)
    {
        const int k1 = tid, k2 = tid + 256, k3 = tid + 512;
        sh[S0O + k1] = (k1 < t0) ? sh[FRO + k1] : NEG_INF;
        sh[S0O + k2] = (k2 < t0) ? sh[FRO + k2] : NEG_INF;
        if (k3 < 576) sh[S0O + k3] = NEG_INF;
        if (tid < 64) sh[LTO + tid] = sh[FRO + t0 + tid];   // Lt[0]
        __syncthreads();
        for (int off = 1; off < t0; off <<= 1) {
            float a1 = sh[S0O + k1]; if (k1 + off < 576) a1 = fmaxf(a1, sh[S0O + k1 + off]);
            float a2 = sh[S0O + k2]; if (k2 + off < 576) a2 = fmaxf(a2, sh[S0O + k2 + off]);
            __syncthreads();
            sh[S0O + k1] = a1; sh[S0O + k2] = a2;
            __syncthreads();
        }
        for (int j = 1; j < 7; ++j) {
            float v = 0.f;
            if (tid < 64)
                v = fmaxf(sh[LTO + (j - 1) * 64 + tid],
                          sh[LTO + (j - 1) * 64 + min(tid + (1 << (j - 1)), 63)]);
            __syncthreads();
            if (tid < 64) sh[LTO + j * 64 + tid] = v;
            __syncthreads();
        }
    }

    floatx4 acc[2][4];
#pragma unroll
    for (int r = 0; r < 2; ++r)
#pragma unroll
        for (int j = 0; j < 4; ++j) acc[r][j] = (floatx4)0.f;

    for (int ck = 0; ck < nchunks; ck += 2) {
        CHUNK_BODY(ck,     pmvA, min(ck + 1, lastc), min(ck + 2, lastc));
        CHUNK_BODY(ck + 1, pmvB, min(ck + 2, lastc), min(ck + 3, lastc));
    }

    // ---- epilogue ----
    {
        const int q = lane >> 4;
#pragma unroll
        for (int r = 0; r < 2; ++r) {
#pragma unroll
            for (int j = 0; j < 4; ++j) {
#pragma unroll
                for (int reg = 0; reg < 4; ++reg) {
                    const int t = t0 + 32 * wr + 16 * r + 4 * q + reg;
                    const int col = 64 * wc + 16 * j + n;
                    out[((size_t)t * BB + b) * EE + col] = acc[r][j][reg];
                }
            }
        }
    }
}

// ============================================================
extern "C" void kernel_launch(void* const* d_in, const int* in_sizes, int n_in,
                              void* d_out, int out_size, void* d_ws, size_t ws_size,
                              hipStream_t stream) {
    const float* v1 = (const float*)d_in[0];
    const float* v2 = (const float*)d_in[1];
    const float* d1 = (const float*)d_in[2];
    const float* d2 = (const float*)d_in[3];
    const float* u  = (const float*)d_in[4];
    float* out = (float*)d_out;

    char* ws = (char*)d_ws;
    float* m   = (float*)ws;                                   // 2 MB
    float* F   = m   + (size_t)TT * SS;
    float* Bvp = F   + (size_t)BB * TT;
    float* d2T = Bvp + (size_t)BB * TT;
    float* FT  = d2T + (size_t)BB * TT;
    float* BvT = FT  + (size_t)BB * TT;
    float* CST = BvT + (size_t)BB * TT;
    float* HT  = CST + (size_t)BB * TT;
    float* CMT = HT  + (size_t)BB * TT;                        // 16*128

    prefixF<<<dim3(BB), dim3(64), 0, stream>>>(d1, d2, u, F, Bvp, d2T, FT,
                                               BvT, CST, CMT, HT);
    calcM3 <<<dim3(TT), dim3(256), 0, stream>>>(FT, BvT, CST, CMT, HT, u, m);
    phaseC_mfma<<<dim3(BB * 8), dim3(256), 0, stream>>>(F, Bvp, d2T, m, v1, v2, out);
}